// Round 13
// baseline (269.799 us; speedup 1.0000x reference)
//
#include <hip/hip_runtime.h>
#include <hip/hip_bf16.h>
#include <stdint.h>

// B=2, LQ=LK=2048, H=1024, NH=16, HD=64
typedef __attribute__((ext_vector_type(8))) short short8;
typedef __attribute__((ext_vector_type(4))) short s16x4;
typedef __attribute__((ext_vector_type(4))) float f32x4;

#define MFMA16(a,b,c)    __builtin_amdgcn_mfma_f32_16x16x32_bf16(a,b,c,0,0,0)
#define MFMA16K16(a,b,c) __builtin_amdgcn_mfma_f32_16x16x16bf16_1k(a,b,c,0,0,0)

static __device__ inline void gload_lds16(const void* g, void* l) {
  __builtin_amdgcn_global_load_lds((const __attribute__((address_space(1))) uint32_t*)g,
                                   (__attribute__((address_space(3))) uint32_t*)l, 16, 0, 0);
}

// ---------------- fused fp32 -> bf16 convert for all 6 tensors ----------------
__global__ __launch_bounds__(256) void cvt_all(
    const float* __restrict__ dh, const float* __restrict__ eh,
    const float* __restrict__ Wq, const float* __restrict__ Wk,
    const float* __restrict__ Wv, const float* __restrict__ Wo,
    __hip_bfloat16* __restrict__ dhb, __hip_bfloat16* __restrict__ ehb,
    __hip_bfloat16* __restrict__ wqb, __hip_bfloat16* __restrict__ wkb,
    __hip_bfloat16* __restrict__ wvb, __hip_bfloat16* __restrict__ wob)
{
  int idx = blockIdx.x * 256 + threadIdx.x;   // 8-element units
  const float* src; __hip_bfloat16* dst; int off;
  if      (idx <  524288) { src=dh; dst=dhb; off=idx; }
  else if (idx < 1048576) { src=eh; dst=ehb; off=idx-524288; }
  else if (idx < 1179648) { src=Wq; dst=wqb; off=idx-1048576; }
  else if (idx < 1310720) { src=Wk; dst=wkb; off=idx-1179648; }
  else if (idx < 1441792) { src=Wv; dst=wvb; off=idx-1310720; }
  else                    { src=Wo; dst=wob; off=idx-1441792; }
  float4 a = ((const float4*)src)[off*2+0];
  float4 b = ((const float4*)src)[off*2+1];
  union { short8 v; __hip_bfloat16 h[8]; } u;
  u.h[0]=__float2bfloat16(a.x); u.h[1]=__float2bfloat16(a.y);
  u.h[2]=__float2bfloat16(a.z); u.h[3]=__float2bfloat16(a.w);
  u.h[4]=__float2bfloat16(b.x); u.h[5]=__float2bfloat16(b.y);
  u.h[6]=__float2bfloat16(b.z); u.h[7]=__float2bfloat16(b.w);
  ((short8*)dst)[off] = u.v;
}

// ---------------- 128x128x(BK=64) bf16 GEMM core: C = A * W^T ----------------
__device__ inline void gemm_core(const __hip_bfloat16* __restrict__ A,
                                 const __hip_bfloat16* __restrict__ W,
                                 int bm, int bn, int K, f32x4 (&acc)[4][4]) {
  __shared__ __hip_bfloat16 sA[128*64];
  __shared__ __hip_bfloat16 sB[128*64];
  const int t = threadIdx.x, lane = t & 63, wvi = t >> 6, g = lane >> 4, i = lane & 15;
  const int wm = wvi >> 1, wn = wvi & 1;
  const f32x4 z4 = {0.f,0.f,0.f,0.f};
  for (int m=0;m<4;m++) for (int n=0;n<4;n++) acc[m][n]=z4;
  const int nkt = K >> 6;
  for (int kt=0; kt<nkt; ++kt) {
    for (int c=0;c<4;c++) {
      int idx = c*256+t, row = idx>>3, slot = idx&7;
      int sc = (slot ^ (row&7))*8;
      gload_lds16(A + (size_t)(bm*128+row)*K + kt*64 + sc, (char*)sA + c*4096 + wvi*1024);
    }
    for (int c=0;c<4;c++) {
      int idx = c*256+t, row = idx>>3, slot = idx&7;
      int sc = (slot ^ (row&7))*8;
      gload_lds16(W + (size_t)(bn*128+row)*K + kt*64 + sc, (char*)sB + c*4096 + wvi*1024);
    }
    __syncthreads();
    short8 af[4][2], bf[4][2];
    for (int m=0;m<4;m++) {
      int row = wm*64 + m*16 + i;
      af[m][0] = *(const short8*)&sA[row*64 + ((g     ^ (row&7)))*8];
      af[m][1] = *(const short8*)&sA[row*64 + (((4+g) ^ (row&7)))*8];
    }
    for (int n=0;n<4;n++) {
      int row = wn*64 + n*16 + i;
      bf[n][0] = *(const short8*)&sB[row*64 + ((g     ^ (row&7)))*8];
      bf[n][1] = *(const short8*)&sB[row*64 + (((4+g) ^ (row&7)))*8];
    }
    for (int m=0;m<4;m++) for (int n=0;n<4;n++) {
      acc[m][n] = MFMA16(af[m][0], bf[n][0], acc[m][n]);
      acc[m][n] = MFMA16(af[m][1], bf[n][1], acc[m][n]);
    }
    __syncthreads();
  }
}

// Fused Q/K/V projection: grid (M/128, N/128, 3). V is written TRANSPOSED to Vt.
__global__ __launch_bounds__(256) void gemm_qkv(
    const __hip_bfloat16* __restrict__ dhb, const __hip_bfloat16* __restrict__ ehb,
    const __hip_bfloat16* __restrict__ wqp, const __hip_bfloat16* __restrict__ wkp,
    const __hip_bfloat16* __restrict__ wvp,
    __hip_bfloat16* __restrict__ Qb, __hip_bfloat16* __restrict__ Kb,
    __hip_bfloat16* __restrict__ Vt) {
  const int zz = blockIdx.z;
  const __hip_bfloat16* A = (zz==0) ? dhb : ehb;
  const __hip_bfloat16* W = (zz==0) ? wqp : (zz==1 ? wkp : wvp);
  f32x4 acc[4][4];
  gemm_core(A, W, blockIdx.x, blockIdx.y, 1024, acc);
  const int t = threadIdx.x, lane=t&63, w_=t>>6, g=lane>>4, i=lane&15;
  const int wm=w_>>1, wn=w_&1;
  if (zz != 2) {
    __hip_bfloat16* C = (zz==0) ? Qb : Kb;
    for (int m=0;m<4;m++) for (int n=0;n<4;n++) for (int r=0;r<4;r++) {
      int row = blockIdx.x*128 + wm*64 + m*16 + 4*g + r;
      int col = blockIdx.y*128 + wn*64 + n*16 + i;
      C[(size_t)row*1024 + col] = __float2bfloat16(acc[m][n][r]);
    }
  } else {
    // write V transposed: Vt[b][h][d][k], lane holds 4 consecutive k (rows)
    for (int m=0;m<4;m++) for (int n=0;n<4;n++) {
      int row0 = blockIdx.x*128 + wm*64 + m*16 + 4*g;   // k-global, 4-aligned
      int bb = row0 >> 11, kin = row0 & 2047;
      int o = blockIdx.y*128 + wn*64 + n*16 + i;
      int hh = o >> 6, dd = o & 63;
      union { s16x4 v; __hip_bfloat16 h4[4]; } u;
      for (int r=0;r<4;r++) u.h4[r] = __float2bfloat16(acc[m][n][r]);
      *(s16x4*)&Vt[((size_t)((bb*16+hh)*64+dd))*2048 + kin] = u.v;
    }
  }
}

// Output projection + bias, fp32 out
__global__ __launch_bounds__(256) void gemm_out(
    const __hip_bfloat16* __restrict__ ctx, const __hip_bfloat16* __restrict__ wop,
    const float* __restrict__ bias, float* __restrict__ out) {
  f32x4 acc[4][4];
  gemm_core(ctx, wop, blockIdx.x, blockIdx.y, 1024, acc);
  const int t = threadIdx.x, lane=t&63, w_=t>>6, g=lane>>4, i=lane&15;
  const int wm=w_>>1, wn=w_&1;
  for (int m=0;m<4;m++) for (int n=0;n<4;n++) for (int r=0;r<4;r++) {
    int row = blockIdx.x*128 + wm*64 + m*16 + 4*g + r;
    int col = blockIdx.y*128 + wn*64 + n*16 + i;
    out[(size_t)row*1024 + col] = acc[m][n][r] + bias[col];
  }
}

// ---------------- Attention, 2-phase shared pair. grid (LQ/128, B*NH), 256 thr ----------------
// Block owns tiles A (q0A) and B (q0A+64) of the same head.
// G: pass1(A)+pass1(B) sharing every K-frag and V-frag read (no stores).
// H: pass2(A)+pass2(B) sharing K-frag reads; ALL weight stores here, pipelined
//    with vmcnt(8) so each kt's 8 stores fly through the next kt's compute.
// LDS 49152: [0,16K) sK dbuf; [16K,32K) sV dbuf; [32K,48K) sT per-wave 4KB.
__global__ __launch_bounds__(256, 2) void attn_gh(
    const __hip_bfloat16* __restrict__ Qb, const __hip_bfloat16* __restrict__ Kb,
    const __hip_bfloat16* __restrict__ Vt, const int* __restrict__ mask,
    float* __restrict__ wout, __hip_bfloat16* __restrict__ ctx)
{
  __shared__ char smem[49152];
  const int t = threadIdx.x, lane = t&63, wv_ = t>>6, g = lane>>4, i = lane&15;
  const int bh = blockIdx.y, b = bh>>4, h = bh&15;
  const int q0A = blockIdx.x*128 + wv_*16;
  const int q0B = q0A + 64;
  const float scale = 0.125f;
  const f32x4 z4 = {0.f,0.f,0.f,0.f};

  short8 qfA[2], qfB[2];
  { const __hip_bfloat16* qr = Qb + (size_t)(b*2048 + q0A + i)*1024 + h*64;
    qfA[0] = *(const short8*)(qr + g*8);
    qfA[1] = *(const short8*)(qr + 32 + g*8);
    const __hip_bfloat16* qr2 = Qb + (size_t)(b*2048 + q0B + i)*1024 + h*64;
    qfB[0] = *(const short8*)(qr2 + g*8);
    qfB[1] = *(const short8*)(qr2 + 32 + g*8); }

  const int* mbase = mask + b*2048;
  char* sT = smem + 32768 + wv_*4096;

#define STAGE_KV(buf, kt_) do { \
    _Pragma("unroll") \
    for (int c=0;c<2;c++) { \
      int idx_ = c*256 + t; int row_ = idx_>>3, slot_ = idx_&7; \
      int sc_ = (slot_ ^ (row_&7)) * 8; \
      gload_lds16(Kb + (size_t)(b*2048 + (kt_)*64 + row_)*1024 + h*64 + sc_, \
                  smem + (buf)*8192 + c*4096 + wv_*1024); \
      gload_lds16(Vt + (size_t)((b*16+h)*64 + row_)*2048 + (kt_)*64 + sc_, \
                  smem + 16384 + (buf)*8192 + c*4096 + wv_*1024); \
    } } while(0)

#define STAGE_K(buf, kt_) do { \
    _Pragma("unroll") \
    for (int c=0;c<2;c++) { \
      int idx_ = c*256 + t; int row_ = idx_>>3, slot_ = idx_&7; \
      int sc_ = (slot_ ^ (row_&7)) * 8; \
      gload_lds16(Kb + (size_t)(b*2048 + (kt_)*64 + row_)*1024 + h*64 + sc_, \
                  smem + (buf)*8192 + c*4096 + wv_*1024); \
    } } while(0)

  // ================= G: pass1(A) + pass1(B), shared K/V frags =================
  f32x4 accA[4], accB[4];
  #pragma unroll
  for (int z=0;z<4;z++) { accA[z]=z4; accB[z]=z4; }
  float lsumA = 0.0f, lsumB = 0.0f;
  int cur = 0;
  STAGE_KV(0, 0);
  __syncthreads();
  for (int kt=0; kt<32; ++kt) {
    if (kt+1 < 32) STAGE_KV(cur^1, kt+1);
    const __hip_bfloat16* sKc = (const __hip_bfloat16*)(smem + cur*8192);
    const __hip_bfloat16* sVc = (const __hip_bfloat16*)(smem + 16384 + cur*8192);
    s16x4 pkA[4], pkB[4];
    #pragma unroll
    for (int cb=0; cb<4; ++cb) {
      int row = cb*16 + i;
      short8 kf0 = *(const short8*)&sKc[row*64 + ((g     ^ (row&7)))*8];
      short8 kf1 = *(const short8*)&sKc[row*64 + (((4+g) ^ (row&7)))*8];
      int4 m4 = *(const int4*)&mbase[kt*64 + cb*16 + 4*g];
      f32x4 stA = MFMA16(kf0, qfA[0], z4);
      stA = MFMA16(kf1, qfA[1], stA);
      f32x4 stB = MFMA16(kf0, qfB[0], z4);
      stB = MFMA16(kf1, qfB[1], stB);
      float a0 = m4.x ? __expf(stA[0]*scale) : 0.0f;
      float a1 = m4.y ? __expf(stA[1]*scale) : 0.0f;
      float a2 = m4.z ? __expf(stA[2]*scale) : 0.0f;
      float a3 = m4.w ? __expf(stA[3]*scale) : 0.0f;
      lsumA += (a0+a1)+(a2+a3);
      float b0 = m4.x ? __expf(stB[0]*scale) : 0.0f;
      float b1 = m4.y ? __expf(stB[1]*scale) : 0.0f;
      float b2 = m4.z ? __expf(stB[2]*scale) : 0.0f;
      float b3 = m4.w ? __expf(stB[3]*scale) : 0.0f;
      lsumB += (b0+b1)+(b2+b3);
      union { s16x4 v; __hip_bfloat16 hh[4]; } ua, ub;
      ua.hh[0]=__float2bfloat16(a0); ua.hh[1]=__float2bfloat16(a1);
      ua.hh[2]=__float2bfloat16(a2); ua.hh[3]=__float2bfloat16(a3);
      ub.hh[0]=__float2bfloat16(b0); ub.hh[1]=__float2bfloat16(b1);
      ub.hh[2]=__float2bfloat16(b2); ub.hh[3]=__float2bfloat16(b3);
      pkA[cb] = ua.v; pkB[cb] = ub.v;
    }
    #pragma unroll
    for (int cb=0; cb<4; ++cb) {
      #pragma unroll
      for (int blk=0; blk<4; ++blk) {
        int vrow = blk*16 + i;
        const s16x4 vtf = *(const s16x4*)&sVc[vrow*64 +
            (((2*cb + (g>>1)) ^ (vrow&7)))*8 + 4*(g&1)];
        accA[blk] = MFMA16K16(pkA[cb], vtf, accA[blk]);
        accB[blk] = MFMA16K16(pkB[cb], vtf, accB[blk]);
      }
    }
    __syncthreads();
    cur ^= 1;
  }

  lsumA += __shfl_xor(lsumA, 16);
  lsumA += __shfl_xor(lsumA, 32);
  lsumB += __shfl_xor(lsumB, 16);
  lsumB += __shfl_xor(lsumB, 32);
  const float linvA = 1.0f / lsumA;   // l^-1 for q = q0A + i
  const float linvB = 1.0f / lsumB;   // l^-1 for q = q0B + i
  { float lrA[4], lrB[4];
    #pragma unroll
    for (int r=0;r<4;r++) {
      lrA[r] = __shfl(linvA, (lane & 48) | (4*g + r));
      lrB[r] = __shfl(linvB, (lane & 48) | (4*g + r));
    }
    #pragma unroll
    for (int blk=0;blk<4;blk++)
      #pragma unroll
      for (int r=0;r<4;r++) {
        int qa = q0A + 4*g + r;
        ctx[(size_t)(b*2048 + qa)*1024 + h*64 + blk*16 + i] =
            __float2bfloat16(accA[blk][r]*lrA[r]);
        int qb = q0B + 4*g + r;
        ctx[(size_t)(b*2048 + qb)*1024 + h*64 + blk*16 + i] =
            __float2bfloat16(accB[blk][r]*lrB[r]);
      } }

  // ================= H: pass2(A) + pass2(B), shared K frags, all stores =================
  float* wrowA = wout + ((size_t)bh*2048 + q0A)*2048;
  float* wrowB = wout + ((size_t)bh*2048 + q0B)*2048;
  cur = 0;
  STAGE_K(0, 0);
  __syncthreads();
  for (int kt=0; kt<32; ++kt) {
    if (kt+1 < 32) STAGE_K(cur^1, kt+1);
    asm volatile("" ::: "memory");
    const __hip_bfloat16* sKc = (const __hip_bfloat16*)(smem + cur*8192);
    f32x4 w4B[4];
    #pragma unroll
    for (int cb=0; cb<4; ++cb) {
      int row = cb*16 + i;
      short8 kf0 = *(const short8*)&sKc[row*64 + ((g     ^ (row&7)))*8];
      short8 kf1 = *(const short8*)&sKc[row*64 + (((4+g) ^ (row&7)))*8];
      int4 m4 = *(const int4*)&mbase[kt*64 + cb*16 + 4*g];
      f32x4 stA = MFMA16(kf0, qfA[0], z4);
      stA = MFMA16(kf1, qfA[1], stA);
      f32x4 wa;
      wa[0] = m4.x ? __expf(stA[0]*scale)*linvA : 0.f;
      wa[1] = m4.y ? __expf(stA[1]*scale)*linvA : 0.f;
      wa[2] = m4.z ? __expf(stA[2]*scale)*linvA : 0.f;
      wa[3] = m4.w ? __expf(stA[3]*scale)*linvA : 0.f;
      *(f32x4*)(sT + i*256 + (((cb*4 + g) ^ i) * 16)) = wa;
      f32x4 stB = MFMA16(kf0, qfB[0], z4);
      stB = MFMA16(kf1, qfB[1], stB);
      f32x4 wb;
      wb[0] = m4.x ? __expf(stB[0]*scale)*linvB : 0.f;
      wb[1] = m4.y ? __expf(stB[1]*scale)*linvB : 0.f;
      wb[2] = m4.z ? __expf(stB[2]*scale)*linvB : 0.f;
      wb[3] = m4.w ? __expf(stB[3]*scale)*linvB : 0.f;
      w4B[cb] = wb;
    }
    // A's coalesced stores (reads of sT precede the B overwrites; per-wave
    // LDS ops execute in order, and sT is wave-private)
    #pragma unroll
    for (int s=0; s<4; ++s) {
      int rho = 4*s + g;
      f32x4 w4 = *(const f32x4*)(sT + rho*256 + ((i ^ rho) * 16));
      __builtin_nontemporal_store(w4,
          (f32x4*)&wrowA[(size_t)rho*2048 + kt*64 + i*4]);
    }
    // B's transpose + coalesced stores
    #pragma unroll
    for (int cb=0; cb<4; ++cb)
      *(f32x4*)(sT + i*256 + (((cb*4 + g) ^ i) * 16)) = w4B[cb];
    #pragma unroll
    for (int s=0; s<4; ++s) {
      int rho = 4*s + g;
      f32x4 w4 = *(const f32x4*)(sT + rho*256 + ((i ^ rho) * 16));
      __builtin_nontemporal_store(w4,
          (f32x4*)&wrowB[(size_t)rho*2048 + kt*64 + i*4]);
    }
    // drain: prev-kt's 8 stores + this kt's 2 stage loads; leave this kt's
    // 8 stores in flight through the next kt's compute
    asm volatile("s_waitcnt vmcnt(8)" ::: "memory");
    __builtin_amdgcn_s_barrier();
    cur ^= 1;
  }
#undef STAGE_KV
#undef STAGE_K
}

// ---------------- launch ----------------
extern "C" void kernel_launch(void* const* d_in, const int* in_sizes, int n_in,
                              void* d_out, int out_size, void* d_ws, size_t ws_size,
                              hipStream_t stream) {
  const float* dh  = (const float*)d_in[0];
  const float* eh  = (const float*)d_in[1];
  const int*  mask = (const int*)d_in[2];
  const float* Wq  = (const float*)d_in[3];
  const float* Wk  = (const float*)d_in[4];
  const float* Wv  = (const float*)d_in[5];
  const float* Wo  = (const float*)d_in[6];
  const float* bo  = (const float*)d_in[7];
  float* out  = (float*)d_out;
  float* wout = out + (size_t)2*2048*1024;   // weights follow output

  char* ws = (char*)d_ws;
  __hip_bfloat16* dhb = (__hip_bfloat16*)(ws + 0);          // 8 MB  [4096][1024]
  __hip_bfloat16* ehb = (__hip_bfloat16*)(ws + 8388608);    // 8 MB
  __hip_bfloat16* wqb = (__hip_bfloat16*)(ws + 16777216);   // 2 MB  [1024][1024]
  __hip_bfloat16* wkb = (__hip_bfloat16*)(ws + 18874368);
  __hip_bfloat16* wvb = (__hip_bfloat16*)(ws + 20971520);
  __hip_bfloat16* wob = (__hip_bfloat16*)(ws + 23068672);
  __hip_bfloat16* Qb  = (__hip_bfloat16*)(ws + 25165824);   // 8 MB
  __hip_bfloat16* Kb  = (__hip_bfloat16*)(ws + 33554432);   // 8 MB
  __hip_bfloat16* Vtb = (__hip_bfloat16*)(ws + 41943040);   // 8 MB  [B][NH][HD][LK]
  __hip_bfloat16* ctxb= (__hip_bfloat16*)(ws + 50331648);   // 8 MB  [4096][1024]

  cvt_all<<<6144, 256, 0, stream>>>(dh, eh, Wq, Wk, Wv, Wo,
                                    dhb, ehb, wqb, wkb, wvb, wob);
  gemm_qkv<<<dim3(32, 8, 3), 256, 0, stream>>>(dhb, ehb, wqb, wkb, wvb, Qb, Kb, Vtb);
  attn_gh<<<dim3(16, 32), 256, 0, stream>>>(Qb, Kb, Vtb, mask, wout, ctxb);
  gemm_out<<<dim3(32, 8), 256, 0, stream>>>(ctxb, wob, bo, out);
}

// Round 14
// 231.044 us; speedup vs baseline: 1.1677x; 1.1677x over previous
//
#include <hip/hip_runtime.h>
#include <hip/hip_bf16.h>
#include <stdint.h>

// B=2, LQ=LK=2048, H=1024, NH=16, HD=64
typedef __attribute__((ext_vector_type(8))) short short8;
typedef __attribute__((ext_vector_type(4))) short s16x4;
typedef __attribute__((ext_vector_type(4))) float f32x4;

#define MFMA16(a,b,c)    __builtin_amdgcn_mfma_f32_16x16x32_bf16(a,b,c,0,0,0)
#define MFMA16K16(a,b,c) __builtin_amdgcn_mfma_f32_16x16x16bf16_1k(a,b,c,0,0,0)

static __device__ inline void gload_lds16(const void* g, void* l) {
  __builtin_amdgcn_global_load_lds((const __attribute__((address_space(1))) uint32_t*)g,
                                   (__attribute__((address_space(3))) uint32_t*)l, 16, 0, 0);
}

// ---------------- fused fp32 -> bf16 convert for all 6 tensors ----------------
__global__ __launch_bounds__(256) void cvt_all(
    const float* __restrict__ dh, const float* __restrict__ eh,
    const float* __restrict__ Wq, const float* __restrict__ Wk,
    const float* __restrict__ Wv, const float* __restrict__ Wo,
    __hip_bfloat16* __restrict__ dhb, __hip_bfloat16* __restrict__ ehb,
    __hip_bfloat16* __restrict__ wqb, __hip_bfloat16* __restrict__ wkb,
    __hip_bfloat16* __restrict__ wvb, __hip_bfloat16* __restrict__ wob)
{
  int idx = blockIdx.x * 256 + threadIdx.x;   // 8-element units
  const float* src; __hip_bfloat16* dst; int off;
  if      (idx <  524288) { src=dh; dst=dhb; off=idx; }
  else if (idx < 1048576) { src=eh; dst=ehb; off=idx-524288; }
  else if (idx < 1179648) { src=Wq; dst=wqb; off=idx-1048576; }
  else if (idx < 1310720) { src=Wk; dst=wkb; off=idx-1179648; }
  else if (idx < 1441792) { src=Wv; dst=wvb; off=idx-1310720; }
  else                    { src=Wo; dst=wob; off=idx-1441792; }
  float4 a = ((const float4*)src)[off*2+0];
  float4 b = ((const float4*)src)[off*2+1];
  union { short8 v; __hip_bfloat16 h[8]; } u;
  u.h[0]=__float2bfloat16(a.x); u.h[1]=__float2bfloat16(a.y);
  u.h[2]=__float2bfloat16(a.z); u.h[3]=__float2bfloat16(a.w);
  u.h[4]=__float2bfloat16(b.x); u.h[5]=__float2bfloat16(b.y);
  u.h[6]=__float2bfloat16(b.z); u.h[7]=__float2bfloat16(b.w);
  ((short8*)dst)[off] = u.v;
}

// ---------------- 128x128x(BK=64) bf16 GEMM core: C = A * W^T ----------------
__device__ inline void gemm_core(const __hip_bfloat16* __restrict__ A,
                                 const __hip_bfloat16* __restrict__ W,
                                 int bm, int bn, int K, f32x4 (&acc)[4][4]) {
  __shared__ __hip_bfloat16 sA[128*64];
  __shared__ __hip_bfloat16 sB[128*64];
  const int t = threadIdx.x, lane = t & 63, wvi = t >> 6, g = lane >> 4, i = lane & 15;
  const int wm = wvi >> 1, wn = wvi & 1;
  const f32x4 z4 = {0.f,0.f,0.f,0.f};
  for (int m=0;m<4;m++) for (int n=0;n<4;n++) acc[m][n]=z4;
  const int nkt = K >> 6;
  for (int kt=0; kt<nkt; ++kt) {
    for (int c=0;c<4;c++) {
      int idx = c*256+t, row = idx>>3, slot = idx&7;
      int sc = (slot ^ (row&7))*8;
      gload_lds16(A + (size_t)(bm*128+row)*K + kt*64 + sc, (char*)sA + c*4096 + wvi*1024);
    }
    for (int c=0;c<4;c++) {
      int idx = c*256+t, row = idx>>3, slot = idx&7;
      int sc = (slot ^ (row&7))*8;
      gload_lds16(W + (size_t)(bn*128+row)*K + kt*64 + sc, (char*)sB + c*4096 + wvi*1024);
    }
    __syncthreads();
    short8 af[4][2], bf[4][2];
    for (int m=0;m<4;m++) {
      int row = wm*64 + m*16 + i;
      af[m][0] = *(const short8*)&sA[row*64 + ((g     ^ (row&7)))*8];
      af[m][1] = *(const short8*)&sA[row*64 + (((4+g) ^ (row&7)))*8];
    }
    for (int n=0;n<4;n++) {
      int row = wn*64 + n*16 + i;
      bf[n][0] = *(const short8*)&sB[row*64 + ((g     ^ (row&7)))*8];
      bf[n][1] = *(const short8*)&sB[row*64 + (((4+g) ^ (row&7)))*8];
    }
    for (int m=0;m<4;m++) for (int n=0;n<4;n++) {
      acc[m][n] = MFMA16(af[m][0], bf[n][0], acc[m][n]);
      acc[m][n] = MFMA16(af[m][1], bf[n][1], acc[m][n]);
    }
    __syncthreads();
  }
}

// Fused Q/K/V projection: grid (M/128, N/128, 3). V is written TRANSPOSED to Vt.
__global__ __launch_bounds__(256) void gemm_qkv(
    const __hip_bfloat16* __restrict__ dhb, const __hip_bfloat16* __restrict__ ehb,
    const __hip_bfloat16* __restrict__ wqp, const __hip_bfloat16* __restrict__ wkp,
    const __hip_bfloat16* __restrict__ wvp,
    __hip_bfloat16* __restrict__ Qb, __hip_bfloat16* __restrict__ Kb,
    __hip_bfloat16* __restrict__ Vt) {
  const int zz = blockIdx.z;
  const __hip_bfloat16* A = (zz==0) ? dhb : ehb;
  const __hip_bfloat16* W = (zz==0) ? wqp : (zz==1 ? wkp : wvp);
  f32x4 acc[4][4];
  gemm_core(A, W, blockIdx.x, blockIdx.y, 1024, acc);
  const int t = threadIdx.x, lane=t&63, w_=t>>6, g=lane>>4, i=lane&15;
  const int wm=w_>>1, wn=w_&1;
  if (zz != 2) {
    __hip_bfloat16* C = (zz==0) ? Qb : Kb;
    for (int m=0;m<4;m++) for (int n=0;n<4;n++) for (int r=0;r<4;r++) {
      int row = blockIdx.x*128 + wm*64 + m*16 + 4*g + r;
      int col = blockIdx.y*128 + wn*64 + n*16 + i;
      C[(size_t)row*1024 + col] = __float2bfloat16(acc[m][n][r]);
    }
  } else {
    // write V transposed: Vt[b][h][d][k], lane holds 4 consecutive k (rows)
    for (int m=0;m<4;m++) for (int n=0;n<4;n++) {
      int row0 = blockIdx.x*128 + wm*64 + m*16 + 4*g;   // k-global, 4-aligned
      int bb = row0 >> 11, kin = row0 & 2047;
      int o = blockIdx.y*128 + wn*64 + n*16 + i;
      int hh = o >> 6, dd = o & 63;
      union { s16x4 v; __hip_bfloat16 h4[4]; } u;
      for (int r=0;r<4;r++) u.h4[r] = __float2bfloat16(acc[m][n][r]);
      *(s16x4*)&Vt[((size_t)((bb*16+hh)*64+dd))*2048 + kin] = u.v;
    }
  }
}

// Output projection + bias, fp32 out
__global__ __launch_bounds__(256) void gemm_out(
    const __hip_bfloat16* __restrict__ ctx, const __hip_bfloat16* __restrict__ wop,
    const float* __restrict__ bias, float* __restrict__ out) {
  f32x4 acc[4][4];
  gemm_core(ctx, wop, blockIdx.x, blockIdx.y, 1024, acc);
  const int t = threadIdx.x, lane=t&63, w_=t>>6, g=lane>>4, i=lane&15;
  const int wm=w_>>1, wn=w_&1;
  for (int m=0;m<4;m++) for (int n=0;n<4;n++) for (int r=0;r<4;r++) {
    int row = blockIdx.x*128 + wm*64 + m*16 + 4*g + r;
    int col = blockIdx.y*128 + wn*64 + n*16 + i;
    out[(size_t)row*1024 + col] = acc[m][n][r] + bias[col];
  }
}

// ---------------- Attention, pair-tile 3-phase. grid (LQ/128, B*NH), 256 thr ----------------
// Block owns tiles A (q0A) and B (q0A+64) of the same head -> phase 2 overlaps
// A's coalesced weight stores with B's pass-1 compute, sharing K-fragment reads.
// LDS 49152: [0,16K) sK dbuf; [16K,32K) sV dbuf; [32K,48K) sT per-wave 4KB.
__global__ __launch_bounds__(256, 2) void attn_pair(
    const __hip_bfloat16* __restrict__ Qb, const __hip_bfloat16* __restrict__ Kb,
    const __hip_bfloat16* __restrict__ Vt, const int* __restrict__ mask,
    float* __restrict__ wout, __hip_bfloat16* __restrict__ ctx)
{
  __shared__ char smem[49152];
  const int t = threadIdx.x, lane = t&63, wv_ = t>>6, g = lane>>4, i = lane&15;
  const int bh = blockIdx.y, b = bh>>4, h = bh&15;
  const int q0A = blockIdx.x*128 + wv_*16;
  const int q0B = q0A + 64;
  const float scale = 0.125f;
  const f32x4 z4 = {0.f,0.f,0.f,0.f};

  short8 qfA[2], qfB[2];
  { const __hip_bfloat16* qr = Qb + (size_t)(b*2048 + q0A + i)*1024 + h*64;
    qfA[0] = *(const short8*)(qr + g*8);
    qfA[1] = *(const short8*)(qr + 32 + g*8);
    const __hip_bfloat16* qr2 = Qb + (size_t)(b*2048 + q0B + i)*1024 + h*64;
    qfB[0] = *(const short8*)(qr2 + g*8);
    qfB[1] = *(const short8*)(qr2 + 32 + g*8); }

  const int* mbase = mask + b*2048;
  char* sT = smem + 32768 + wv_*4096;

#define STAGE_KV(buf, kt_) do { \
    _Pragma("unroll") \
    for (int c=0;c<2;c++) { \
      int idx_ = c*256 + t; int row_ = idx_>>3, slot_ = idx_&7; \
      int sc_ = (slot_ ^ (row_&7)) * 8; \
      gload_lds16(Kb + (size_t)(b*2048 + (kt_)*64 + row_)*1024 + h*64 + sc_, \
                  smem + (buf)*8192 + c*4096 + wv_*1024); \
      gload_lds16(Vt + (size_t)((b*16+h)*64 + row_)*2048 + (kt_)*64 + sc_, \
                  smem + 16384 + (buf)*8192 + c*4096 + wv_*1024); \
    } } while(0)

#define STAGE_K(buf, kt_) do { \
    _Pragma("unroll") \
    for (int c=0;c<2;c++) { \
      int idx_ = c*256 + t; int row_ = idx_>>3, slot_ = idx_&7; \
      int sc_ = (slot_ ^ (row_&7)) * 8; \
      gload_lds16(Kb + (size_t)(b*2048 + (kt_)*64 + row_)*1024 + h*64 + sc_, \
                  smem + (buf)*8192 + c*4096 + wv_*1024); \
    } } while(0)

  // ================= phase 1: pass1(A) =================
  f32x4 acc[4];
  for (int z=0;z<4;z++) acc[z] = z4;
  float lsum = 0.0f;
  int cur = 0;
  STAGE_KV(0, 0);
  __syncthreads();
  for (int kt=0; kt<32; ++kt) {
    if (kt+1 < 32) STAGE_KV(cur^1, kt+1);
    const __hip_bfloat16* sKc = (const __hip_bfloat16*)(smem + cur*8192);
    const __hip_bfloat16* sVc = (const __hip_bfloat16*)(smem + 16384 + cur*8192);
    #pragma unroll
    for (int cb=0; cb<4; ++cb) {
      int row = cb*16 + i;
      short8 kf0 = *(const short8*)&sKc[row*64 + ((g     ^ (row&7)))*8];
      short8 kf1 = *(const short8*)&sKc[row*64 + (((4+g) ^ (row&7)))*8];
      f32x4 st = MFMA16(kf0, qfA[0], z4);
      st = MFMA16(kf1, qfA[1], st);
      int4 m4 = *(const int4*)&mbase[kt*64 + cb*16 + 4*g];
      float p0 = m4.x ? __expf(st[0]*scale) : 0.0f;
      float p1 = m4.y ? __expf(st[1]*scale) : 0.0f;
      float p2 = m4.z ? __expf(st[2]*scale) : 0.0f;
      float p3 = m4.w ? __expf(st[3]*scale) : 0.0f;
      lsum += (p0+p1)+(p2+p3);
      union { s16x4 v; __hip_bfloat16 hh[4]; } pk;
      pk.hh[0]=__float2bfloat16(p0); pk.hh[1]=__float2bfloat16(p1);
      pk.hh[2]=__float2bfloat16(p2); pk.hh[3]=__float2bfloat16(p3);
      #pragma unroll
      for (int blk=0; blk<4; ++blk) {
        int vrow = blk*16 + i;
        const s16x4 vtf = *(const s16x4*)&sVc[vrow*64 +
            (((2*cb + (g>>1)) ^ (vrow&7)))*8 + 4*(g&1)];
        acc[blk] = MFMA16K16(pk.v, vtf, acc[blk]);
      }
    }
    __syncthreads();
    cur ^= 1;
  }
  lsum += __shfl_xor(lsum, 16);
  lsum += __shfl_xor(lsum, 32);
  const float linvA = 1.0f / lsum;   // l^-1 for q = q0A + i
  { float linvr[4];
    #pragma unroll
    for (int r=0;r<4;r++) linvr[r] = __shfl(linvA, (lane & 48) | (4*g + r));
    #pragma unroll
    for (int blk=0;blk<4;blk++)
      #pragma unroll
      for (int r=0;r<4;r++) {
        int q = q0A + 4*g + r;
        ctx[(size_t)(b*2048 + q)*1024 + h*64 + blk*16 + i] =
            __float2bfloat16(acc[blk][r]*linvr[r]);
      } }

  // ================= phase 2: pass2(A) + pass1(B), shared K-frags =================
  for (int z=0;z<4;z++) acc[z] = z4;
  lsum = 0.0f;
  float* wrowA = wout + ((size_t)bh*2048 + q0A)*2048;
  cur = 0;
  STAGE_KV(0, 0);
  __syncthreads();
  for (int kt=0; kt<32; ++kt) {
    if (kt+1 < 32) STAGE_KV(cur^1, kt+1);
    asm volatile("" ::: "memory");
    const __hip_bfloat16* sKc = (const __hip_bfloat16*)(smem + cur*8192);
    const __hip_bfloat16* sVc = (const __hip_bfloat16*)(smem + 16384 + cur*8192);
    s16x4 pkB[4];
    #pragma unroll
    for (int cb=0; cb<4; ++cb) {
      int row = cb*16 + i;
      short8 kf0 = *(const short8*)&sKc[row*64 + ((g     ^ (row&7)))*8];
      short8 kf1 = *(const short8*)&sKc[row*64 + (((4+g) ^ (row&7)))*8];
      int4 m4 = *(const int4*)&mbase[kt*64 + cb*16 + 4*g];
      // A: recompute S^T -> normalized w -> sT
      f32x4 stA = MFMA16(kf0, qfA[0], z4);
      stA = MFMA16(kf1, qfA[1], stA);
      f32x4 w4;
      w4[0] = m4.x ? __expf(stA[0]*scale)*linvA : 0.f;
      w4[1] = m4.y ? __expf(stA[1]*scale)*linvA : 0.f;
      w4[2] = m4.z ? __expf(stA[2]*scale)*linvA : 0.f;
      w4[3] = m4.w ? __expf(stA[3]*scale)*linvA : 0.f;
      *(f32x4*)(sT + i*256 + (((cb*4 + g) ^ i) * 16)) = w4;
      // B: S^T -> p (unnormalized)
      f32x4 stB = MFMA16(kf0, qfB[0], z4);
      stB = MFMA16(kf1, qfB[1], stB);
      float p0 = m4.x ? __expf(stB[0]*scale) : 0.0f;
      float p1 = m4.y ? __expf(stB[1]*scale) : 0.0f;
      float p2 = m4.z ? __expf(stB[2]*scale) : 0.0f;
      float p3 = m4.w ? __expf(stB[3]*scale) : 0.0f;
      lsum += (p0+p1)+(p2+p3);
      union { s16x4 v; __hip_bfloat16 hh[4]; } pk;
      pk.hh[0]=__float2bfloat16(p0); pk.hh[1]=__float2bfloat16(p1);
      pk.hh[2]=__float2bfloat16(p2); pk.hh[3]=__float2bfloat16(p3);
      pkB[cb] = pk.v;
    }
    // A's coalesced stores — issued BEFORE B's PV so they drain under the MFMAs
    #pragma unroll
    for (int s=0; s<4; ++s) {
      int rho = 4*s + g;
      f32x4 w4 = *(const f32x4*)(sT + rho*256 + ((i ^ rho) * 16));
      __builtin_nontemporal_store(w4,
          (f32x4*)&wrowA[(size_t)rho*2048 + kt*64 + i*4]);
    }
    // B's PV
    #pragma unroll
    for (int cb=0; cb<4; ++cb) {
      #pragma unroll
      for (int blk=0; blk<4; ++blk) {
        int vrow = blk*16 + i;
        const s16x4 vtf = *(const s16x4*)&sVc[vrow*64 +
            (((2*cb + (g>>1)) ^ (vrow&7)))*8 + 4*(g&1)];
        acc[blk] = MFMA16K16(pkB[cb], vtf, acc[blk]);
      }
    }
    // 4 stage loads (oldest) done; this kt's 4 stores stay in flight
    asm volatile("s_waitcnt vmcnt(4)" ::: "memory");
    __builtin_amdgcn_s_barrier();
    cur ^= 1;
  }
  lsum += __shfl_xor(lsum, 16);
  lsum += __shfl_xor(lsum, 32);
  const float linvB = 1.0f / lsum;   // l^-1 for q = q0B + i
  { float linvr[4];
    #pragma unroll
    for (int r=0;r<4;r++) linvr[r] = __shfl(linvB, (lane & 48) | (4*g + r));
    #pragma unroll
    for (int blk=0;blk<4;blk++)
      #pragma unroll
      for (int r=0;r<4;r++) {
        int q = q0B + 4*g + r;
        ctx[(size_t)(b*2048 + q)*1024 + h*64 + blk*16 + i] =
            __float2bfloat16(acc[blk][r]*linvr[r]);
      } }

  // ================= phase 3: pass2(B) =================
  float* wrowB = wout + ((size_t)bh*2048 + q0B)*2048;
  cur = 0;
  STAGE_K(0, 0);
  __syncthreads();
  for (int kt=0; kt<32; ++kt) {
    if (kt+1 < 32) STAGE_K(cur^1, kt+1);
    asm volatile("" ::: "memory");
    const __hip_bfloat16* sKc = (const __hip_bfloat16*)(smem + cur*8192);
    #pragma unroll
    for (int cb=0; cb<4; ++cb) {
      int row = cb*16 + i;
      short8 kf0 = *(const short8*)&sKc[row*64 + ((g     ^ (row&7)))*8];
      short8 kf1 = *(const short8*)&sKc[row*64 + (((4+g) ^ (row&7)))*8];
      f32x4 st = MFMA16(kf0, qfB[0], z4);
      st = MFMA16(kf1, qfB[1], st);
      int4 m4 = *(const int4*)&mbase[kt*64 + cb*16 + 4*g];
      f32x4 w4;
      w4[0] = m4.x ? __expf(st[0]*scale)*linvB : 0.f;
      w4[1] = m4.y ? __expf(st[1]*scale)*linvB : 0.f;
      w4[2] = m4.z ? __expf(st[2]*scale)*linvB : 0.f;
      w4[3] = m4.w ? __expf(st[3]*scale)*linvB : 0.f;
      *(f32x4*)(sT + i*256 + (((cb*4 + g) ^ i) * 16)) = w4;
    }
    #pragma unroll
    for (int s=0; s<4; ++s) {
      int rho = 4*s + g;
      f32x4 w4 = *(const f32x4*)(sT + rho*256 + ((i ^ rho) * 16));
      __builtin_nontemporal_store(w4,
          (f32x4*)&wrowB[(size_t)rho*2048 + kt*64 + i*4]);
    }
    asm volatile("s_waitcnt vmcnt(4)" ::: "memory");
    __builtin_amdgcn_s_barrier();
    cur ^= 1;
  }
#undef STAGE_KV
#undef STAGE_K
}

// ---------------- launch ----------------
extern "C" void kernel_launch(void* const* d_in, const int* in_sizes, int n_in,
                              void* d_out, int out_size, void* d_ws, size_t ws_size,
                              hipStream_t stream) {
  const float* dh  = (const float*)d_in[0];
  const float* eh  = (const float*)d_in[1];
  const int*  mask = (const int*)d_in[2];
  const float* Wq  = (const float*)d_in[3];
  const float* Wk  = (const float*)d_in[4];
  const float* Wv  = (const float*)d_in[5];
  const float* Wo  = (const float*)d_in[6];
  const float* bo  = (const float*)d_in[7];
  float* out  = (float*)d_out;
  float* wout = out + (size_t)2*2048*1024;   // weights follow output

  char* ws = (char*)d_ws;
  __hip_bfloat16* dhb = (__hip_bfloat16*)(ws + 0);          // 8 MB  [4096][1024]
  __hip_bfloat16* ehb = (__hip_bfloat16*)(ws + 8388608);    // 8 MB
  __hip_bfloat16* wqb = (__hip_bfloat16*)(ws + 16777216);   // 2 MB  [1024][1024]
  __hip_bfloat16* wkb = (__hip_bfloat16*)(ws + 18874368);
  __hip_bfloat16* wvb = (__hip_bfloat16*)(ws + 20971520);
  __hip_bfloat16* wob = (__hip_bfloat16*)(ws + 23068672);
  __hip_bfloat16* Qb  = (__hip_bfloat16*)(ws + 25165824);   // 8 MB
  __hip_bfloat16* Kb  = (__hip_bfloat16*)(ws + 33554432);   // 8 MB
  __hip_bfloat16* Vtb = (__hip_bfloat16*)(ws + 41943040);   // 8 MB  [B][NH][HD][LK]
  __hip_bfloat16* ctxb= (__hip_bfloat16*)(ws + 50331648);   // 8 MB  [4096][1024]

  cvt_all<<<6144, 256, 0, stream>>>(dh, eh, Wq, Wk, Wv, Wo,
                                    dhb, ehb, wqb, wkb, wvb, wob);
  gemm_qkv<<<dim3(32, 8, 3), 256, 0, stream>>>(dhb, ehb, wqb, wkb, wvb, Qb, Kb, Vtb);
  attn_pair<<<dim3(16, 32), 256, 0, stream>>>(Qb, Kb, Vtb, mask, wout, ctxb);
  gemm_out<<<dim3(32, 8), 256, 0, stream>>>(ctxb, wob, bo, out);
}